// Round 2
// baseline (377.168 us; speedup 1.0000x reference)
//
#include <hip/hip_runtime.h>
#include <hip/hip_bf16.h>

// Problem constants (from reference)
#define BB    16
#define LQ    64
#define LD    2048
#define HH    1024
#define DIM   128
#define MAXK  513          // LD/PF + 1 with PF=4
#define NCH   3            // ceil(513 / 256) cluster chunks for simmax

typedef __attribute__((ext_vector_type(8))) short short8;
typedef __attribute__((ext_vector_type(4))) float f32x4;

__device__ __forceinline__ float b2f(ushort u) {
    union { float f; unsigned int u32; } c; c.u32 = ((unsigned int)u) << 16; return c.f;
}
__device__ __forceinline__ ushort f2b(float f) {
    unsigned int x = __float_as_uint(f);
    return (ushort)((x + 0x7fffu + ((x >> 16) & 1u)) >> 16);
}

// ---------------------------------------------------------------------------
// prep: W [H][DIM] fp32 -> Wt_hi/Wt_lo [DIM][H] bf16 (transposed + split)
__global__ __launch_bounds__(256) void prep_kernel(const float* __restrict__ W,
                                                   ushort* __restrict__ Wt_hi,
                                                   ushort* __restrict__ Wt_lo) {
    int idx = blockIdx.x * 256 + threadIdx.x;   // < H*DIM = 131072
    int h = idx >> 7;        // row in H
    int n = idx & 127;       // col in DIM
    float x = W[idx];
    ushort hi = f2b(x);
    float r = x - b2f(hi);
    Wt_hi[n * HH + h] = hi;
    Wt_lo[n * HH + h] = f2b(r);
}

// ---------------------------------------------------------------------------
// per-batch cluster count k[b] = max(sum(d_mask),2)//pf + 1
__global__ __launch_bounds__(256) void kb_kernel(const int* __restrict__ d_mask,
                                                 const int* __restrict__ pf,
                                                 int* __restrict__ kvals) {
    int b = blockIdx.x, t = threadIdx.x;
    int lane = t & 63, wave = t >> 6;
    int s = 0;
    for (int i = t; i < LD; i += 256) s += (d_mask[b * LD + i] > 0) ? 1 : 0;
    #pragma unroll
    for (int m = 1; m < 64; m <<= 1) s += __shfl_xor(s, m);
    __shared__ int red[4];
    if (lane == 0) red[wave] = s;
    __syncthreads();
    if (t == 0) {
        int v = red[0] + red[1] + red[2] + red[3];
        if (v < 2) v = 2;
        int pfv = pf[0];
        if (pfv < 1 || pfv > LD) pfv = 4;   // defensive
        kvals[b] = v / pfv + 1;
    }
}

// ---------------------------------------------------------------------------
// Encode: out[M][DIM] = normalize(X[M][H] @ W + b) * mask
// fp32 inputs; GEMM via split-bf16 (hi+lo) MFMA, 3 passes -> ~fp32 accuracy.
// 128x128 output tile per block, BK=32, MFMA 16x16x32 bf16.
__global__ __launch_bounds__(256) void encode_kernel(
    const float*  __restrict__ X,       // [M][H] fp32
    const ushort* __restrict__ Wt_hi,   // [DIM][H] bf16
    const ushort* __restrict__ Wt_lo,   // [DIM][H] bf16
    const float*  __restrict__ bias,    // [DIM] fp32
    const int*    __restrict__ mask,    // [M]
    float*        __restrict__ out)     // [M][DIM] fp32
{
    __shared__ __align__(16) ushort Ah[128 * 48];
    __shared__ __align__(16) ushort Al[128 * 48];
    __shared__ __align__(16) ushort Bh[128 * 48];
    __shared__ __align__(16) ushort Bl[128 * 48];

    const int t = threadIdx.x;
    const int wave = t >> 6, lane = t & 63;
    const int m16 = lane & 15, quad = lane >> 4;
    const long row0 = (long)blockIdx.x * 128;

    f32x4 acc[2][8];
    #pragma unroll
    for (int i = 0; i < 2; ++i)
        #pragma unroll
        for (int j = 0; j < 8; ++j) acc[i][j] = (f32x4){0.f, 0.f, 0.f, 0.f};

    for (int k0 = 0; k0 < HH; k0 += 32) {
        // stage B (already bf16 split in global): 128 n-rows x 32 k
        #pragma unroll
        for (int it = 0; it < 2; ++it) {
            int s = it * 256 + t;            // 0..511
            int r = s >> 2;                  // 0..127
            int c8 = (s & 3) * 8;            // 0,8,16,24
            *(uint4*)(&Bh[r * 48 + c8]) = *(const uint4*)(Wt_hi + (long)r * HH + k0 + c8);
            *(uint4*)(&Bl[r * 48 + c8]) = *(const uint4*)(Wt_lo + (long)r * HH + k0 + c8);
        }
        // stage A (fp32 -> split bf16): 128 rows x 32 k
        #pragma unroll
        for (int it = 0; it < 4; ++it) {
            int s = it * 256 + t;            // 0..1023
            int r = s >> 3;                  // 0..127
            int col = (s & 7) * 4;           // 0..28 step 4
            float4 v = *(const float4*)(X + (row0 + r) * HH + k0 + col);
            ushort4 h, l;
            h.x = f2b(v.x); l.x = f2b(v.x - b2f(h.x));
            h.y = f2b(v.y); l.y = f2b(v.y - b2f(h.y));
            h.z = f2b(v.z); l.z = f2b(v.z - b2f(h.z));
            h.w = f2b(v.w); l.w = f2b(v.w - b2f(h.w));
            *(ushort4*)(&Ah[r * 48 + col]) = h;
            *(ushort4*)(&Al[r * 48 + col]) = l;
        }
        __syncthreads();

        short8 ah0 = *(const short8*)(&Ah[((wave * 2 + 0) * 16 + m16) * 48 + quad * 8]);
        short8 ah1 = *(const short8*)(&Ah[((wave * 2 + 1) * 16 + m16) * 48 + quad * 8]);
        short8 al0 = *(const short8*)(&Al[((wave * 2 + 0) * 16 + m16) * 48 + quad * 8]);
        short8 al1 = *(const short8*)(&Al[((wave * 2 + 1) * 16 + m16) * 48 + quad * 8]);
        #pragma unroll
        for (int ct = 0; ct < 8; ++ct) {
            short8 bh = *(const short8*)(&Bh[(ct * 16 + m16) * 48 + quad * 8]);
            short8 bl = *(const short8*)(&Bl[(ct * 16 + m16) * 48 + quad * 8]);
            acc[0][ct] = __builtin_amdgcn_mfma_f32_16x16x32_bf16(ah0, bh, acc[0][ct], 0, 0, 0);
            acc[0][ct] = __builtin_amdgcn_mfma_f32_16x16x32_bf16(ah0, bl, acc[0][ct], 0, 0, 0);
            acc[0][ct] = __builtin_amdgcn_mfma_f32_16x16x32_bf16(al0, bh, acc[0][ct], 0, 0, 0);
            acc[1][ct] = __builtin_amdgcn_mfma_f32_16x16x32_bf16(ah1, bh, acc[1][ct], 0, 0, 0);
            acc[1][ct] = __builtin_amdgcn_mfma_f32_16x16x32_bf16(ah1, bl, acc[1][ct], 0, 0, 0);
            acc[1][ct] = __builtin_amdgcn_mfma_f32_16x16x32_bf16(al1, bh, acc[1][ct], 0, 0, 0);
        }
        __syncthreads();
    }

    // epilogue: bias + L2-normalize per row + mask, store fp32
    float bia[8];
    #pragma unroll
    for (int ct = 0; ct < 8; ++ct) bia[ct] = bias[ct * 16 + m16];

    #pragma unroll
    for (int rt = 0; rt < 2; ++rt) {
        #pragma unroll
        for (int r = 0; r < 4; ++r) {
            long rowg = row0 + (wave * 2 + rt) * 16 + quad * 4 + r;
            float v[8];
            float ss = 0.f;
            #pragma unroll
            for (int ct = 0; ct < 8; ++ct) {
                v[ct] = acc[rt][ct][r] + bia[ct];
                ss += v[ct] * v[ct];
            }
            // reduce across the 16 lanes holding this row (same quad)
            ss += __shfl_xor(ss, 1);
            ss += __shfl_xor(ss, 2);
            ss += __shfl_xor(ss, 4);
            ss += __shfl_xor(ss, 8);
            float scale = 1.0f / fmaxf(sqrtf(ss), 1e-12f);
            scale *= (float)mask[rowg];
            #pragma unroll
            for (int ct = 0; ct < 8; ++ct)
                out[rowg * DIM + ct * 16 + m16] = v[ct] * scale;
        }
    }
}

// ---------------------------------------------------------------------------
// Scatter: sums[b][seg][d] += d_repr[b][t][d]; counts[b][seg] += 1
__global__ __launch_bounds__(256) void scatter_kernel(
    const float* __restrict__ d_repr,
    const int*   __restrict__ d_mask,
    const int*   __restrict__ labels,
    const int*   __restrict__ kvals,
    float*       __restrict__ sums,
    float*       __restrict__ counts)
{
    int t = threadIdx.x;
    long token = (long)blockIdx.x * 2 + (t >> 7);
    int d = t & 127;
    int b = (int)(token >> 11);   // / LD
    if (d_mask[token] > 0) {
        int seg = labels[token] % kvals[b];
        atomicAdd(&sums[((long)b * MAXK + seg) * DIM + d], d_repr[token * DIM + d]);
        if (d == 0) atomicAdd(&counts[b * MAXK + seg], 1.0f);
    }
}

// ---------------------------------------------------------------------------
// Finalize pooling: mean, L2-normalize, pad-mask (in place over sums)
__global__ __launch_bounds__(128) void finalize_kernel(
    const int*   __restrict__ kvals,
    float*       __restrict__ sums,     // in-out -> becomes d_pool
    const float* __restrict__ counts)
{
    long bk = blockIdx.x;               // 0..B*MAXK-1
    int b = (int)(bk / MAXK), kk = (int)(bk % MAXK);
    int d = threadIdx.x;
    int lane = d & 63, wave = d >> 6;
    float c = counts[bk];
    float mean = sums[bk * DIM + d] / fmaxf(c, 1.0f);
    float ss = mean * mean;
    #pragma unroll
    for (int m = 1; m < 64; m <<= 1) ss += __shfl_xor(ss, m);
    __shared__ float red[2];
    if (lane == 0) red[wave] = ss;
    __syncthreads();
    float tot = red[0] + red[1];
    float scale = 1.0f / fmaxf(sqrtf(tot), 1e-12f);
    if (kk >= kvals[b]) scale = 0.0f;
    sums[bk * DIM + d] = mean * scale;
}

// ---------------------------------------------------------------------------
// Sim + per-row max over a 256-cluster chunk. One cluster per lane.
__global__ __launch_bounds__(256) void simmax_kernel(
    const float* __restrict__ q_repr,   // [B][LQ][DIM]
    const float* __restrict__ d_pool,   // [B][MAXK][DIM]
    const int*   __restrict__ kvals,
    float*       __restrict__ pmax)     // [B][NCH][LQ]
{
    __shared__ float qs[64 * 132];
    __shared__ float red[4][64];
    int b = blockIdx.x / NCH;
    int chunk = blockIdx.x % NCH;
    int t = threadIdx.x, w = t >> 6, lane = t & 63;

    for (int idx = t; idx < LQ * DIM; idx += 256) {
        int r = idx >> 7, d = idx & 127;
        qs[r * 132 + d] = q_repr[(long)b * LQ * DIM + idx];
    }
    __syncthreads();

    int kk = chunk * 256 + t;
    bool vload = kk < MAXK;
    const float4* dp4 = (const float4*)(d_pool + ((long)b * MAXK + (vload ? kk : 0)) * DIM);

    float acc[64];
    #pragma unroll
    for (int r = 0; r < 64; ++r) acc[r] = 0.f;

    for (int d4 = 0; d4 < 32; ++d4) {
        float4 c = vload ? dp4[d4] : make_float4(0.f, 0.f, 0.f, 0.f);
        #pragma unroll
        for (int r = 0; r < 64; ++r) {
            float4 q = *(const float4*)(&qs[r * 132 + d4 * 4]);
            acc[r] += q.x * c.x + q.y * c.y + q.z * c.z + q.w * c.w;
        }
    }

    int kb = kvals[b];
    float mine = -1e4f;
    #pragma unroll
    for (int r = 0; r < 64; ++r) {
        float v = (kk < kb) ? acc[r] : -1e4f;
        v = fmaxf(v, __shfl_xor(v, 1));
        v = fmaxf(v, __shfl_xor(v, 2));
        v = fmaxf(v, __shfl_xor(v, 4));
        v = fmaxf(v, __shfl_xor(v, 8));
        v = fmaxf(v, __shfl_xor(v, 16));
        v = fmaxf(v, __shfl_xor(v, 32));
        if (lane == r) mine = v;     // lane r keeps row-r wave max
    }
    red[w][lane] = mine;
    __syncthreads();
    if (t < 64) {
        float m = fmaxf(fmaxf(red[0][t], red[1][t]), fmaxf(red[2][t], red[3][t]));
        pmax[((long)b * NCH + chunk) * 64 + t] = m;
    }
}

// ---------------------------------------------------------------------------
// Final: per batch, max over chunks, *q_mask, sum over rows -> fp32 score
__global__ __launch_bounds__(64) void final_kernel(
    const float* __restrict__ pmax,
    const int*   __restrict__ q_mask,
    float*       __restrict__ out)
{
    int b = blockIdx.x, r = threadIdx.x;
    float m = fmaxf(fmaxf(pmax[((long)b * NCH + 0) * 64 + r],
                          pmax[((long)b * NCH + 1) * 64 + r]),
                          pmax[((long)b * NCH + 2) * 64 + r]);
    m *= (float)q_mask[b * LQ + r];
    #pragma unroll
    for (int sh = 1; sh < 64; sh <<= 1) m += __shfl_xor(m, sh);
    if (r == 0) out[b] = m;
}

// ---------------------------------------------------------------------------
extern "C" void kernel_launch(void* const* d_in, const int* in_sizes, int n_in,
                              void* d_out, int out_size, void* d_ws, size_t ws_size,
                              hipStream_t stream) {
    const float* q_hidden = (const float*)d_in[0];
    const float* d_hidden = (const float*)d_in[1];
    const float* W        = (const float*)d_in[2];
    const float* bias     = (const float*)d_in[3];
    const int*   q_mask   = (const int*)d_in[4];
    const int*   d_mask   = (const int*)d_in[5];
    const int*   labels   = (const int*)d_in[6];
    const int*   pf       = (const int*)d_in[7];

    float* ws     = (float*)d_ws;
    float* d_repr = ws;                                   // 16*2048*128 = 4,194,304 f
    float* q_repr = d_repr + (long)BB * LD * DIM;         // 131,072 f
    float* sums   = q_repr + (long)BB * LQ * DIM;         // 1,050,624 f
    float* counts = sums + (long)BB * MAXK * DIM;         // 8,208 f
    float* pmaxb  = counts + BB * MAXK;                   // 16*3*64 = 3,072 f
    int*   kvals  = (int*)(pmaxb + BB * NCH * 64);        // 16
    ushort* Wt_hi = (ushort*)(kvals + 16);                // 131,072 bf16
    ushort* Wt_lo = Wt_hi + (long)DIM * HH;               // 131,072 bf16

    // zero segment sums + counts (ws is poisoned before every launch)
    hipMemsetAsync(sums, 0, (size_t)(BB * MAXK * DIM + BB * MAXK) * sizeof(float), stream);

    prep_kernel<<<(HH * DIM) / 256, 256, 0, stream>>>(W, Wt_hi, Wt_lo);
    kb_kernel<<<BB, 256, 0, stream>>>(d_mask, pf, kvals);
    encode_kernel<<<(BB * LD) / 128, 256, 0, stream>>>(d_hidden, Wt_hi, Wt_lo, bias, d_mask, d_repr);
    encode_kernel<<<(BB * LQ) / 128, 256, 0, stream>>>(q_hidden, Wt_hi, Wt_lo, bias, q_mask, q_repr);
    scatter_kernel<<<(BB * LD) / 2, 256, 0, stream>>>(d_repr, d_mask, labels, kvals, sums, counts);
    finalize_kernel<<<BB * MAXK, 128, 0, stream>>>(kvals, sums, counts);
    simmax_kernel<<<BB * NCH, 256, 0, stream>>>(q_repr, sums, kvals, pmaxb);
    final_kernel<<<BB, 64, 0, stream>>>(pmaxb, q_mask, (float*)d_out);
}

// Round 3
// 369.703 us; speedup vs baseline: 1.0202x; 1.0202x over previous
//
#include <hip/hip_runtime.h>
#include <hip/hip_bf16.h>

// Problem constants (from reference)
#define BB    16
#define LQ    64
#define LD    2048
#define HH    1024
#define DIM   128
#define MAXK  513          // LD/PF + 1 with PF=4
#define NCH   3            // 256-cluster chunks for simmax
#define RSP   4            // row-splits (16 q-rows each) for simmax
#define DGRID 512          // d-encode blocks (32768 / 64)
#define QGRID 16           // q-encode blocks (1024 / 64)

typedef __attribute__((ext_vector_type(8))) short short8;
typedef __attribute__((ext_vector_type(4))) float f32x4;

__device__ __forceinline__ float b2f(ushort u) {
    union { float f; unsigned int u32; } c; c.u32 = ((unsigned int)u) << 16; return c.f;
}
__device__ __forceinline__ ushort f2b_rn(float f) {   // round-to-nearest (prep only)
    unsigned int x = __float_as_uint(f);
    return (ushort)((x + 0x7fffu + ((x >> 16) & 1u)) >> 16);
}

// ---------------------------------------------------------------------------
// prep: W [H][DIM] fp32 -> Wt_hi/Wt_lo [DIM][H] bf16 (transposed + split)
__global__ __launch_bounds__(256) void prep_kernel(const float* __restrict__ W,
                                                   ushort* __restrict__ Wt_hi,
                                                   ushort* __restrict__ Wt_lo) {
    int idx = blockIdx.x * 256 + threadIdx.x;   // < H*DIM = 131072
    int h = idx >> 7;        // row in H
    int n = idx & 127;       // col in DIM
    float x = W[idx];
    ushort hi = f2b_rn(x);
    float r = x - b2f(hi);
    Wt_hi[n * HH + h] = hi;
    Wt_lo[n * HH + h] = f2b_rn(r);
}

// ---------------------------------------------------------------------------
// per-batch cluster count k[b] = max(sum(d_mask),2)//pf + 1
__global__ __launch_bounds__(256) void kb_kernel(const int* __restrict__ d_mask,
                                                 const int* __restrict__ pf,
                                                 int* __restrict__ kvals) {
    int b = blockIdx.x, t = threadIdx.x;
    int lane = t & 63, wave = t >> 6;
    int s = 0;
    for (int i = t; i < LD; i += 256) s += (d_mask[b * LD + i] > 0) ? 1 : 0;
    #pragma unroll
    for (int m = 1; m < 64; m <<= 1) s += __shfl_xor(s, m);
    __shared__ int red[4];
    if (lane == 0) red[wave] = s;
    __syncthreads();
    if (t == 0) {
        int v = red[0] + red[1] + red[2] + red[3];
        if (v < 2) v = 2;
        int pfv = pf[0];
        if (pfv < 1 || pfv > LD) pfv = 4;   // defensive
        kvals[b] = v / pfv + 1;
    }
}

// ---------------------------------------------------------------------------
// Encode (d and q fused in one grid): out = normalize(X @ W + b) * mask
// 64-row tile / block (4 waves x 16 rows). A: global->reg direct (per-wave
// exclusive rows). B: LDS double-buffered, register-prefetched, ONE barrier
// per K=32 chunk. Split-bf16 (truncate) x 3 MFMA passes for fp32 accuracy.
__global__ __launch_bounds__(256) void encode_kernel(
    const float*  __restrict__ Xd,      // [32768][H]
    const float*  __restrict__ Xq,      // [1024][H]
    const ushort* __restrict__ Wt_hi,   // [DIM][H] bf16
    const ushort* __restrict__ Wt_lo,   // [DIM][H] bf16
    const float*  __restrict__ bias,    // [DIM]
    const int*    __restrict__ mask_d,
    const int*    __restrict__ mask_q,
    float*        __restrict__ out_d,   // [32768][DIM]
    float*        __restrict__ out_q)   // [1024][DIM]
{
    __shared__ __align__(16) ushort Bh[2][128 * 40];
    __shared__ __align__(16) ushort Bl[2][128 * 40];

    const int bid = blockIdx.x;
    const float* X; const int* mask; float* out; long row0;
    if (bid < DGRID) { X = Xd; mask = mask_d; out = out_d; row0 = (long)bid * 64; }
    else             { X = Xq; mask = mask_q; out = out_q; row0 = (long)(bid - DGRID) * 64; }

    const int t = threadIdx.x;
    const int wave = t >> 6, lane = t & 63;
    const int m16 = lane & 15, quad = lane >> 4;

    // A: this lane streams row (row0 + wave*16 + m16), k-cols quad*8..+7 per chunk
    const float* ap = X + (row0 + wave * 16 + m16) * HH + quad * 8;

    // B staging: thread t loads row sn, 16 ushorts at k-offset sk
    const int sn = t >> 1, sk = (t & 1) * 16;
    const ushort* bhp = Wt_hi + (long)sn * HH + sk;
    const ushort* blp = Wt_lo + (long)sn * HH + sk;
    const int soff = sn * 40 + sk;

    f32x4 acc[8];
    #pragma unroll
    for (int j = 0; j < 8; ++j) acc[j] = (f32x4){0.f, 0.f, 0.f, 0.f};

    // ---- prologue: chunk 0 ----
    float4 a0 = *(const float4*)(ap);
    float4 a1 = *(const float4*)(ap + 4);
    {
        uint4 h0 = *(const uint4*)(bhp), h1 = *(const uint4*)(bhp + 8);
        uint4 l0 = *(const uint4*)(blp), l1 = *(const uint4*)(blp + 8);
        *(uint4*)(&Bh[0][soff]) = h0; *(uint4*)(&Bh[0][soff + 8]) = h1;
        *(uint4*)(&Bl[0][soff]) = l0; *(uint4*)(&Bl[0][soff + 8]) = l1;
    }

    for (int c = 0; c < 32; ++c) {
        __syncthreads();
        const int cur = c & 1;

        // prefetch next chunk (global loads in flight under this chunk's MFMAs)
        float4 na0, na1; uint4 nh0, nh1, nl0, nl1;
        if (c < 31) {
            const ushort* ph = bhp + (c + 1) * 32;
            const ushort* pl = blp + (c + 1) * 32;
            nh0 = *(const uint4*)(ph); nh1 = *(const uint4*)(ph + 8);
            nl0 = *(const uint4*)(pl); nl1 = *(const uint4*)(pl + 8);
            na0 = *(const float4*)(ap + (c + 1) * 32);
            na1 = *(const float4*)(ap + (c + 1) * 32 + 4);
        }

        // convert current A fragment: fp32 -> (hi, lo) bf16 by truncation
        float av[8];
        *(float4*)(av) = a0; *(float4*)(av + 4) = a1;
        short8 ah, al;
        #pragma unroll
        for (int j = 0; j < 8; ++j) {
            unsigned int ux = __float_as_uint(av[j]);
            ah[j] = (short)(ux >> 16);
            float hif = __uint_as_float(ux & 0xffff0000u);
            al[j] = (short)(__float_as_uint(av[j] - hif) >> 16);
        }

        #pragma unroll
        for (int ct = 0; ct < 8; ++ct) {
            short8 bh = *(const short8*)(&Bh[cur][(ct * 16 + m16) * 40 + quad * 8]);
            short8 bl = *(const short8*)(&Bl[cur][(ct * 16 + m16) * 40 + quad * 8]);
            acc[ct] = __builtin_amdgcn_mfma_f32_16x16x32_bf16(ah, bh, acc[ct], 0, 0, 0);
            acc[ct] = __builtin_amdgcn_mfma_f32_16x16x32_bf16(ah, bl, acc[ct], 0, 0, 0);
            acc[ct] = __builtin_amdgcn_mfma_f32_16x16x32_bf16(al, bh, acc[ct], 0, 0, 0);
        }

        if (c < 31) {
            const int nxt = cur ^ 1;
            *(uint4*)(&Bh[nxt][soff]) = nh0; *(uint4*)(&Bh[nxt][soff + 8]) = nh1;
            *(uint4*)(&Bl[nxt][soff]) = nl0; *(uint4*)(&Bl[nxt][soff + 8]) = nl1;
            a0 = na0; a1 = na1;
        }
    }

    // epilogue: bias + L2-normalize per row + mask
    float bia[8];
    #pragma unroll
    for (int ct = 0; ct < 8; ++ct) bia[ct] = bias[ct * 16 + m16];

    #pragma unroll
    for (int r = 0; r < 4; ++r) {
        long rowg = row0 + wave * 16 + quad * 4 + r;
        float v[8];
        float ss = 0.f;
        #pragma unroll
        for (int ct = 0; ct < 8; ++ct) {
            v[ct] = acc[ct][r] + bia[ct];
            ss += v[ct] * v[ct];
        }
        ss += __shfl_xor(ss, 1);
        ss += __shfl_xor(ss, 2);
        ss += __shfl_xor(ss, 4);
        ss += __shfl_xor(ss, 8);
        float scale = 1.0f / fmaxf(sqrtf(ss), 1e-12f);
        scale *= (float)mask[rowg];
        #pragma unroll
        for (int ct = 0; ct < 8; ++ct)
            out[rowg * DIM + ct * 16 + m16] = v[ct] * scale;
    }
}

// ---------------------------------------------------------------------------
// Scatter via LDS aggregation: block = (batch, 16-dim slice). No global
// atomics, no global memset needed (each block fully owns its output slice).
__global__ __launch_bounds__(256) void scatter_kernel(
    const float* __restrict__ d_repr,
    const int*   __restrict__ d_mask,
    const int*   __restrict__ labels,
    const int*   __restrict__ kvals,
    float*       __restrict__ sums,     // [B][MAXK][DIM]
    float*       __restrict__ counts)   // [B][MAXK]
{
    __shared__ float ls[MAXK * 16];     // 32832 B
    __shared__ float lc[MAXK];          // 2052 B (used by slice 0)
    int b = blockIdx.x >> 3, sl = blockIdx.x & 7;
    int t = threadIdx.x;

    for (int i = t; i < MAXK * 16; i += 256) ls[i] = 0.f;
    if (sl == 0) for (int i = t; i < MAXK; i += 256) lc[i] = 0.f;
    __syncthreads();

    int kb = kvals[b];
    int d = t & 15;
    for (int tok = t >> 4; tok < LD; tok += 16) {
        if (d_mask[b * LD + tok] > 0) {
            int seg = labels[b * LD + tok] % kb;
            atomicAdd(&ls[seg * 16 + d],
                      d_repr[((long)b * LD + tok) * DIM + sl * 16 + d]);
            if (sl == 0 && d == 0) atomicAdd(&lc[seg], 1.0f);
        }
    }
    __syncthreads();

    for (int i = t; i < MAXK * 16; i += 256) {
        int seg = i >> 4, dd = i & 15;
        sums[((long)b * MAXK + seg) * DIM + sl * 16 + dd] = ls[i];
    }
    if (sl == 0) for (int i = t; i < MAXK; i += 256) counts[b * MAXK + i] = lc[i];
}

// ---------------------------------------------------------------------------
// Finalize pooling: mean, L2-normalize, pad-mask (in place over sums)
__global__ __launch_bounds__(128) void finalize_kernel(
    const int*   __restrict__ kvals,
    float*       __restrict__ sums,     // in-out -> becomes d_pool
    const float* __restrict__ counts)
{
    long bk = blockIdx.x;               // 0..B*MAXK-1
    int b = (int)(bk / MAXK), kk = (int)(bk % MAXK);
    int d = threadIdx.x;
    int lane = d & 63, wave = d >> 6;
    float c = counts[bk];
    float mean = sums[bk * DIM + d] / fmaxf(c, 1.0f);
    float ss = mean * mean;
    #pragma unroll
    for (int m = 1; m < 64; m <<= 1) ss += __shfl_xor(ss, m);
    __shared__ float red[2];
    if (lane == 0) red[wave] = ss;
    __syncthreads();
    float tot = red[0] + red[1];
    float scale = 1.0f / fmaxf(sqrtf(tot), 1e-12f);
    if (kk >= kvals[b]) scale = 0.0f;
    sums[bk * DIM + d] = mean * scale;
}

// ---------------------------------------------------------------------------
// Sim + max: block = (batch, 256-cluster chunk, 16-row slice).
// One cluster per thread, 16 row-accumulators per lane.
__global__ __launch_bounds__(256) void simmax_kernel(
    const float* __restrict__ q_repr,   // [B][LQ][DIM]
    const float* __restrict__ d_pool,   // [B][MAXK][DIM]
    const int*   __restrict__ kvals,
    float*       __restrict__ pmax)     // [B][NCH][RSP][16]
{
    __shared__ float qs[16 * 132];
    __shared__ float red[4][16];
    int bid = blockIdx.x;
    int b = bid / (NCH * RSP);
    int rem = bid % (NCH * RSP);
    int chunk = rem / RSP, rs = rem % RSP;
    int t = threadIdx.x, w = t >> 6, lane = t & 63;

    for (int idx = t; idx < 16 * DIM; idx += 256) {
        int r = idx >> 7, d = idx & 127;
        qs[r * 132 + d] = q_repr[((long)b * LQ + rs * 16 + r) * DIM + d];
    }
    __syncthreads();

    int kk = chunk * 256 + t;
    bool vload = kk < MAXK;
    const float4* dp4 = (const float4*)(d_pool + ((long)b * MAXK + (vload ? kk : 0)) * DIM);

    float acc[16];
    #pragma unroll
    for (int r = 0; r < 16; ++r) acc[r] = 0.f;

    for (int d4 = 0; d4 < 32; ++d4) {
        float4 c = vload ? dp4[d4] : make_float4(0.f, 0.f, 0.f, 0.f);
        #pragma unroll
        for (int r = 0; r < 16; ++r) {
            float4 q = *(const float4*)(&qs[r * 132 + d4 * 4]);
            acc[r] += q.x * c.x + q.y * c.y + q.z * c.z + q.w * c.w;
        }
    }

    int kb = kvals[b];
    float mine = -1e4f;
    #pragma unroll
    for (int r = 0; r < 16; ++r) {
        float v = (kk < kb) ? acc[r] : -1e4f;
        v = fmaxf(v, __shfl_xor(v, 1));
        v = fmaxf(v, __shfl_xor(v, 2));
        v = fmaxf(v, __shfl_xor(v, 4));
        v = fmaxf(v, __shfl_xor(v, 8));
        v = fmaxf(v, __shfl_xor(v, 16));
        v = fmaxf(v, __shfl_xor(v, 32));
        if (lane == r) mine = v;        // lane r keeps row-r wave max
    }
    if (lane < 16) red[w][lane] = mine;
    __syncthreads();
    if (t < 16) {
        float m = fmaxf(fmaxf(red[0][t], red[1][t]), fmaxf(red[2][t], red[3][t]));
        pmax[(((long)b * NCH + chunk) * RSP + rs) * 16 + t] = m;
    }
}

// ---------------------------------------------------------------------------
// Final: per batch, max over chunks, *q_mask, sum over rows -> fp32 score
__global__ __launch_bounds__(64) void final_kernel(
    const float* __restrict__ pmax,
    const int*   __restrict__ q_mask,
    float*       __restrict__ out)
{
    int b = blockIdx.x, r = threadIdx.x;
    int rs = r >> 4, lr = r & 15;
    float m = -3e38f;
    #pragma unroll
    for (int c = 0; c < NCH; ++c)
        m = fmaxf(m, pmax[(((long)b * NCH + c) * RSP + rs) * 16 + lr]);
    m *= (float)q_mask[b * LQ + r];
    #pragma unroll
    for (int sh = 1; sh < 64; sh <<= 1) m += __shfl_xor(m, sh);
    if (r == 0) out[b] = m;
}

// ---------------------------------------------------------------------------
extern "C" void kernel_launch(void* const* d_in, const int* in_sizes, int n_in,
                              void* d_out, int out_size, void* d_ws, size_t ws_size,
                              hipStream_t stream) {
    const float* q_hidden = (const float*)d_in[0];
    const float* d_hidden = (const float*)d_in[1];
    const float* W        = (const float*)d_in[2];
    const float* bias     = (const float*)d_in[3];
    const int*   q_mask   = (const int*)d_in[4];
    const int*   d_mask   = (const int*)d_in[5];
    const int*   labels   = (const int*)d_in[6];
    const int*   pf       = (const int*)d_in[7];

    float* ws     = (float*)d_ws;
    float* d_repr = ws;                                   // 4,194,304 f
    float* q_repr = d_repr + (long)BB * LD * DIM;         // 131,072 f
    float* sums   = q_repr + (long)BB * LQ * DIM;         // 1,050,624 f
    float* counts = sums + (long)BB * MAXK * DIM;         // 8,208 f
    float* pmaxb  = counts + BB * MAXK;                   // 3,072 f
    int*   kvals  = (int*)(pmaxb + BB * NCH * RSP * 16);  // 16
    ushort* Wt_hi = (ushort*)(kvals + 16);                // 131,072 bf16
    ushort* Wt_lo = Wt_hi + (long)DIM * HH;               // 131,072 bf16

    prep_kernel<<<(HH * DIM) / 256, 256, 0, stream>>>(W, Wt_hi, Wt_lo);
    kb_kernel<<<BB, 256, 0, stream>>>(d_mask, pf, kvals);
    encode_kernel<<<DGRID + QGRID, 256, 0, stream>>>(d_hidden, q_hidden, Wt_hi, Wt_lo,
                                                     bias, d_mask, q_mask, d_repr, q_repr);
    scatter_kernel<<<BB * 8, 256, 0, stream>>>(d_repr, d_mask, labels, kvals, sums, counts);
    finalize_kernel<<<BB * MAXK, 128, 0, stream>>>(kvals, sums, counts);
    simmax_kernel<<<BB * NCH * RSP, 256, 0, stream>>>(q_repr, sums, kvals, pmaxb);
    final_kernel<<<BB, 64, 0, stream>>>(pmaxb, q_mask, (float*)d_out);
}